// Round 7
// baseline (459.474 us; speedup 1.0000x reference)
//
#include <hip/hip_runtime.h>

#define NM 23        // 3*K - 1, K = 8

__device__ __forceinline__ float softplus_f(float v) {
  // stable: max(v,0) + log(1 + exp(-|v|))
  return fmaxf(v, 0.f) + __logf(1.f + __expf(-fabsf(v)));
}

// ---------------------------------------------------------------------------
// Single fused kernel. Grid = (B/64) row-blocks x 4 d-slices = 2048 blocks,
// 256 threads (4 waves), lane = row.
//
// MADE masks are exactly triangular, so with wave-uniform output indices the
// masks become LOOP TRUNCATIONS on the raw weights (no prep, no masking):
//   layer1: h1[i] sees d <= i%63            -> trip i+1 (i<63), 1 (i=63)
//   layer2: h2[j] sees i%63 <= j            -> trip j+1 (+ i=63 term)
//   layer3: p[(m,d)] sees k < d             -> trip min(d,32)  (26% FMA cut)
// Each d-slice block recomputes layers 1+2 for its 64 rows, truncated to the
// JMAX h2-columns its d-range needs.
//
// ROUND-6 BUG (fixed): x staging used rr=t>>4 with 256 threads -> only rows
// 0..15 staged. Now: cols 0..31 via 2x256 float4 (rr=idx>>3), slice via
// rr=t>>2. 64 rows x 48 cols fully covered.
// ---------------------------------------------------------------------------
__global__ __launch_bounds__(256) void fused_kernel(
    const float* __restrict__ x,
    const float* __restrict__ W1, const float* __restrict__ b1,
    const float* __restrict__ W2, const float* __restrict__ b2,
    const float* __restrict__ W3, const float* __restrict__ b3,
    float* __restrict__ out, float* __restrict__ ldws, int B) {
  __shared__ float xs[64][49];    // cols 0..31: x[0..31]; cols 32..47: x slice
  __shared__ float h1s[64][33];   // cols 0..31: h1[i<32]; col 32: h1[63]; zs later
  __shared__ float h2s[64][33];
  __shared__ float ldp[4][64];

  const int t = threadIdx.x;
  const int rb = blockIdx.x >> 2;       // row-block
  const int ds = blockIdx.x & 3;        // d-slice: d in [ds*16, ds*16+16)
  const int b0 = rb * 64;
  // max h2/h1 column this slice's k-loops touch: k < min(d,32), d <= ds*16+15
  const int JMAX = (ds * 16 + 15 < 32) ? (ds * 16 + 15) : 32;

  // ---- stage x cols 0..31 (layer input): 64 rows x 8 float4 ----
  #pragma unroll
  for (int u = 0; u < 2; ++u) {
    const int idx = t + u * 256;          // 0..511
    const int rr = idx >> 3;              // 0..63
    const int c4 = (idx & 7) * 4;         // 0,4,...,28
    const float4 v = *reinterpret_cast<const float4*>(
        x + (size_t)(b0 + rr) * 64 + c4);
    xs[rr][c4 + 0] = v.x; xs[rr][c4 + 1] = v.y;
    xs[rr][c4 + 2] = v.z; xs[rr][c4 + 3] = v.w;
  }
  // ---- stage x slice cols [ds*16, ds*16+16): 64 rows x 4 float4 ----
  {
    const int rr = t >> 2, c4 = (t & 3) * 4;
    const float4 v = *reinterpret_cast<const float4*>(
        x + (size_t)(b0 + rr) * 64 + ds * 16 + c4);
    xs[rr][32 + c4 + 0] = v.x; xs[rr][32 + c4 + 1] = v.y;
    xs[rr][32 + c4 + 2] = v.z; xs[rr][32 + c4 + 3] = v.w;
  }
  __syncthreads();

  const int r  = t & 63;                                  // lane = row
  const int wv = __builtin_amdgcn_readfirstlane(t >> 6);  // wave 0..3

  // ---- layer 1 (truncated): i in {wv, wv+4, ...} < JMAX, plus i=63 ----
  for (int i = wv; i < JMAX; i += 4) {                    // i uniform per wave
    const float* wrow = W1 + i * 64;                      // contiguous in d
    float acc = b1[i];
    for (int dd = 0; dd <= i; ++dd)                       // exact mask via trip
      acc = fmaf(xs[r][dd], wrow[dd], acc);
    h1s[r][i] = fmaxf(acc, 0.f);
  }
  if (wv == 3) {                                          // i=63: deg 1
    h1s[r][32] = fmaxf(fmaf(xs[r][0], W1[63 * 64], b1[63]), 0.f);
  }
  __syncthreads();

  // ---- layer 2 (truncated): j in {wv, wv+4, ...} < JMAX ----
  for (int j = wv; j < JMAX; j += 4) {                    // j uniform per wave
    const float* wrow = W2 + j * 64;                      // contiguous in i
    float acc = fmaf(h1s[r][32], wrow[63], b2[j]);        // i=63 term
    for (int i2 = 0; i2 <= j; ++i2)                       // exact mask via trip
      acc = fmaf(h1s[r][i2], wrow[i2], acc);
    h2s[r][j] = fmaxf(acc, 0.f);
  }
  __syncthreads();

  // ---- h2 row into registers (only JMAX cols are valid/needed) ----
  float h2r[32];
  #pragma unroll
  for (int k = 0; k < 32; ++k)
    if (k < JMAX) h2r[k] = h2s[r][k];

  float ldacc = 0.f;

  // ---- layer 3 (truncated) + spline: 4 d's per thread ----
  #pragma unroll 1
  for (int di = 0; di < 4; ++di) {
    const int dloc = wv * 4 + di;                          // 0..15, uniform
    const int dU = __builtin_amdgcn_readfirstlane(ds * 16 + dloc);
    const int kmax = (dU < 32) ? dU : 32;                  // uniform trip

    float p[NM];
    if (kmax == 32) {                                      // fast path: d>=32
      #pragma unroll
      for (int m = 0; m < NM; ++m) {
        const float* wrow = W3 + ((size_t)(m * 64 + dU)) * 32;
        float acc = b3[m * 64 + dU];
        #pragma unroll
        for (int kk = 0; kk < 32; ++kk) acc = fmaf(h2r[kk], wrow[kk], acc);
        p[m] = acc;
      }
    } else {
      #pragma unroll
      for (int m = 0; m < NM; ++m) {
        const float* wrow = W3 + ((size_t)(m * 64 + dU)) * 32;
        float acc = b3[m * 64 + dU];
        for (int kk = 0; kk < kmax; ++kk) acc = fmaf(h2r[kk], wrow[kk], acc);
        p[m] = acc;
      }
    }

    const float xv = xs[r][32 + dloc];
    const float xc = fminf(fmaxf(xv, -3.f), 3.f);

    // softmax over widths logits p[0..7]
    float mw = p[0];
    #pragma unroll
    for (int k = 1; k < 8; ++k) mw = fmaxf(mw, p[k]);
    float ew[8], sw = 0.f;
    #pragma unroll
    for (int k = 0; k < 8; ++k) { ew[k] = __expf(p[k] - mw); sw += ew[k]; }
    const float invw = 1.f / sw;

    // softmax over heights logits p[8..15]
    float mh = p[8];
    #pragma unroll
    for (int k = 1; k < 8; ++k) mh = fmaxf(mh, p[8 + k]);
    float eh[8], sh = 0.f;
    #pragma unroll
    for (int k = 0; k < 8; ++k) { eh[k] = __expf(p[8 + k] - mh); sh += eh[k]; }
    const float invh = 1.f / sh;

    const float WSC = 1.0f - 1e-3f * 8.0f;   // 1 - MIN_BIN_WIDTH*K
    float cumw[9], cumh[9];
    cumw[0] = -3.f; cumh[0] = -3.f;
    float cw = 0.f, ch = 0.f;
    #pragma unroll
    for (int k = 0; k < 7; ++k) {
      cw += 1e-3f + WSC * (ew[k] * invw);
      ch += 1e-3f + WSC * (eh[k] * invh);
      cumw[k + 1] = fmaf(6.f, cw, -3.f);
      cumh[k + 1] = fmaf(6.f, ch, -3.f);
    }
    cumw[8] = 3.f; cumh[8] = 3.f;

    float derivs[9];
    derivs[0] = 1.f; derivs[8] = 1.f;
    #pragma unroll
    for (int k = 0; k < 7; ++k) derivs[k + 1] = 1e-3f + softplus_f(p[16 + k]);

    // bin select: idx = sum(xc >= cumw[k]+EPS) - 1, clipped to [0,7]
    float xk = cumw[0], xk1 = cumw[1];
    float yk = cumh[0], yk1 = cumh[1];
    float dk = derivs[0], dk1 = derivs[1];
    #pragma unroll
    for (int k = 1; k < 8; ++k) {
      const bool s = xc >= cumw[k] + 1e-6f;
      xk  = s ? cumw[k]       : xk;
      xk1 = s ? cumw[k + 1]   : xk1;
      yk  = s ? cumh[k]       : yk;
      yk1 = s ? cumh[k + 1]   : yk1;
      dk  = s ? derivs[k]     : dk;
      dk1 = s ? derivs[k + 1] : dk1;
    }

    const float wk = xk1 - xk, hk = yk1 - yk;
    const float invwk = 1.f / wk;
    const float delta = hk * invwk;
    const float theta = (xc - xk) * invwk;
    const float omt = 1.f - theta;
    const float tt = theta * omt;
    const float th2 = theta * theta;
    const float num = hk * (delta * th2 + dk * tt);
    const float den = delta + (dk + dk1 - 2.f * delta) * tt;
    const float yv = yk + num / den;
    const float dnum = delta * delta * (dk1 * th2 + 2.f * delta * tt + dk * omt * omt);
    const float ldv = __logf(dnum) - 2.f * __logf(den);

    const bool inside = (xv >= -3.f) && (xv <= 3.f);
    h1s[r][dloc] = inside ? yv : xv;     // zs overlay: h1s dead after layer 2
    ldacc += inside ? ldv : 0.f;
  }

  ldp[wv][r] = ldacc;
  __syncthreads();

  // ---- coalesced z write from zs overlay ----
  {
    const int row = t >> 2, c4 = (t & 3) * 4;
    const float4 v = make_float4(h1s[row][c4 + 0], h1s[row][c4 + 1],
                                 h1s[row][c4 + 2], h1s[row][c4 + 3]);
    *reinterpret_cast<float4*>(
        out + ((size_t)(b0 + row) * 64) + ds * 16 + c4) = v;
  }
  // ---- log-det partial -> workspace (plain store, no atomics) ----
  if (t < 64) {
    const float s = ldp[0][t] + ldp[1][t] + ldp[2][t] + ldp[3][t];
    ldws[(size_t)ds * B + b0 + t] = s;
  }
}

// ---------------------------------------------------------------------------
// Sum the 4 d-slice log-det partials into the output.
// ---------------------------------------------------------------------------
__global__ __launch_bounds__(256) void ld_reduce(
    const float* __restrict__ ldws, float* __restrict__ out, int B) {
  const int idx = blockIdx.x * 256 + threadIdx.x;
  if (idx < B) {
    out[(size_t)B * 64 + idx] = ldws[idx] + ldws[B + idx] +
                                ldws[2 * B + idx] + ldws[3 * B + idx];
  }
}

extern "C" void kernel_launch(void* const* d_in, const int* in_sizes, int n_in,
                              void* d_out, int out_size, void* d_ws, size_t ws_size,
                              hipStream_t stream) {
  const float* x  = (const float*)d_in[0];
  const float* W1 = (const float*)d_in[1];
  const float* b1 = (const float*)d_in[2];
  const float* W2 = (const float*)d_in[3];
  const float* b2 = (const float*)d_in[4];
  const float* W3 = (const float*)d_in[5];
  const float* b3 = (const float*)d_in[6];
  float* out  = (float*)d_out;
  float* ldws = (float*)d_ws;           // 4*B floats = 512 KB

  const int B = in_sizes[0] / 64;       // 32768

  fused_kernel<<<(B / 64) * 4, 256, 0, stream>>>(
      x, W1, b1, W2, b2, W3, b3, out, ldws, B);

  ld_reduce<<<(B + 255) / 256, 256, 0, stream>>>(ldws, out, B);
}

// Round 8
// 164.473 us; speedup vs baseline: 2.7936x; 2.7936x over previous
//
#include <hip/hip_runtime.h>

#define NM 23        // 3*K - 1, K = 8

typedef float v2f __attribute__((ext_vector_type(2)));

__device__ __forceinline__ float softplus_f(float v) {
  // stable: max(v,0) + log(1 + exp(-|v|))
  return fmaxf(v, 0.f) + __logf(1.f + __expf(-fabsf(v)));
}

// ---------------------------------------------------------------------------
// Kernel 1: layers 1+2 (inline MADE masks) + W3t/b3t prep + log-det zero.
// 64 rows/block, 1024 threads (16 waves), lane = row. Grid = B/64 = 512.
// Coverage: gidx = blockIdx*1024+t spans 524288 >= 47104 (W3t), 1472 (b3t),
// 32768 (ld zero). R4 lesson: verify coverage arithmetic explicitly.
// Inline masks OK here: layers 1+2 are only ~384 FMA/thread.
// ---------------------------------------------------------------------------
__global__ __launch_bounds__(1024, 4) void h2_prep_kernel(
    const float* __restrict__ x,
    const float* __restrict__ W1, const float* __restrict__ b1,
    const float* __restrict__ W2, const float* __restrict__ b2,
    const float* __restrict__ W3, const float* __restrict__ b3,
    float* __restrict__ h2out, float* __restrict__ W3t,
    float* __restrict__ b3t, float* __restrict__ ld_out, int B) {
  __shared__ float xs[64][65];     // overlaid by h2s[64][33] after layer 2
  __shared__ float h1s[64][65];

  const int t = threadIdx.x;
  const int b0 = blockIdx.x * 64;
  const int gidx = blockIdx.x * 1024 + t;

  // ---- side work: W3t[d][m][k] = W3[m*64+d][k] * (k<d); b3t; ld zero ----
  if (gidx < 64 * NM * 32) {
    const int d = gidx / (NM * 32);
    const int rem = gidx - d * (NM * 32);
    const int m = rem >> 5, k = rem & 31;
    W3t[gidx] = (k < d) ? W3[(m * 64 + d) * 32 + k] : 0.f;
  }
  if (gidx < 64 * NM) {
    const int d = gidx / NM, m = gidx - d * NM;
    b3t[gidx] = b3[m * 64 + d];
  }
  if (gidx < B) ld_out[gidx] = 0.f;

  // ---- stage x tile: one float4 per thread (1024 thr = 64 rows) ----
  {
    const int rr = t >> 4, c4 = (t & 15) * 4;
    const float4 v =
        *reinterpret_cast<const float4*>(x + (size_t)b0 * 64 + (size_t)t * 4);
    xs[rr][c4 + 0] = v.x; xs[rr][c4 + 1] = v.y;
    xs[rr][c4 + 2] = v.z; xs[rr][c4 + 3] = v.w;
  }
  __syncthreads();

  const int r  = t & 63;                                  // lane = row
  const int wv = __builtin_amdgcn_readfirstlane(t >> 6);  // wave 0..15

  // ---- layer 1: h1[r][i], i in [wv*4, wv*4+4); mask (dd < (i%63)+1) ----
  {
    float acc1[4];
    #pragma unroll
    for (int ii = 0; ii < 4; ++ii) acc1[ii] = b1[wv * 4 + ii];
    #pragma unroll 4
    for (int dd = 0; dd < 64; ++dd) {
      const float xv = xs[r][dd];
      #pragma unroll
      for (int ii = 0; ii < 4; ++ii) {
        const int i = wv * 4 + ii;
        const int deg = (i % 63) + 1;                       // uniform
        const float w = (dd < deg) ? W1[i * 64 + dd] : 0.f; // uniform select
        acc1[ii] = fmaf(xv, w, acc1[ii]);
      }
    }
    #pragma unroll
    for (int ii = 0; ii < 4; ++ii) h1s[r][wv * 4 + ii] = fmaxf(acc1[ii], 0.f);
  }
  __syncthreads();   // xs reads done -> reusable as h2s

  // ---- layer 2: h2[r][j], j in [wv*2, wv*2+2); mask (i<=j || i==63) ----
  {
    float* h2s = &xs[0][0];   // overlay: h2s[row*33 + j]
    float acc2[2];
    #pragma unroll
    for (int jj = 0; jj < 2; ++jj) acc2[jj] = b2[wv * 2 + jj];
    #pragma unroll 4
    for (int i2 = 0; i2 < 64; ++i2) {
      const float hv = h1s[r][i2];
      #pragma unroll
      for (int jj = 0; jj < 2; ++jj) {
        const int j = wv * 2 + jj;
        const bool on = (i2 <= j) || (i2 == 63);            // uniform
        const float w = on ? W2[j * 64 + i2] : 0.f;         // uniform select
        acc2[jj] = fmaf(hv, w, acc2[jj]);
      }
    }
    #pragma unroll
    for (int jj = 0; jj < 2; ++jj)
      h2s[r * 33 + wv * 2 + jj] = fmaxf(acc2[jj], 0.f);
  }
  __syncthreads();

  // coalesced h2 store: threads 0..511, one float4 each
  if (t < 512) {
    const float* h2s = &xs[0][0];
    const int row = t >> 3, c4 = (t & 7) * 4;
    const float4 v = make_float4(h2s[row * 33 + c4 + 0], h2s[row * 33 + c4 + 1],
                                 h2s[row * 33 + c4 + 2], h2s[row * 33 + c4 + 3]);
    *reinterpret_cast<float4*>(h2out + (size_t)b0 * 32 + (size_t)t * 4) = v;
  }
}

// ---------------------------------------------------------------------------
// Kernel 2: layer 3 + RQ spline (R5-proven structure). Grid = (B/64)*4 =
// 2048 blocks, 256 threads, lane = row, 4 d's/thread.
// NEW vs R5: k-loop uses float2 packed math -> v_pk_fma_f32, halving the
// instruction count of the dominant 736-FMA loop. Pairs formed in registers
// from conflict-free scalar LDS reads (stride-33 stays odd).
// ---------------------------------------------------------------------------
__global__ __launch_bounds__(256) void spline_kernel(
    const float* __restrict__ x, const float* __restrict__ h2in,
    const float* __restrict__ W3t, const float* __restrict__ b3t,
    float* __restrict__ out, int B) {
  __shared__ float h2s[64][33];
  __shared__ float xz[64][17];    // x slice in, z staging out (same owner/elem)
  __shared__ float ldp[4][64];

  const int t = threadIdx.x;
  const int rb = blockIdx.x >> 2;       // row-block
  const int ds = blockIdx.x & 3;        // d-slice: columns [ds*16, ds*16+16)
  const int b0 = rb * 64;

  // stage h2 tile: 64 rows x 32 cols, coalesced float4
  #pragma unroll
  for (int u = 0; u < 2; ++u) {
    const int idx = t + u * 256;
    const int row = idx >> 3, c4 = (idx & 7) * 4;
    const float4 v = *reinterpret_cast<const float4*>(
        h2in + (size_t)b0 * 32 + (size_t)idx * 4);
    h2s[row][c4 + 0] = v.x; h2s[row][c4 + 1] = v.y;
    h2s[row][c4 + 2] = v.z; h2s[row][c4 + 3] = v.w;
  }
  // stage x slice: 64 rows x 16 cols, coalesced float4
  {
    const int row = t >> 2, c4 = (t & 3) * 4;
    const float4 v = *reinterpret_cast<const float4*>(
        x + ((size_t)(b0 + row) * 64) + ds * 16 + c4);
    xz[row][c4 + 0] = v.x; xz[row][c4 + 1] = v.y;
    xz[row][c4 + 2] = v.z; xz[row][c4 + 3] = v.w;
  }
  __syncthreads();

  const int r  = t & 63;                                  // lane = row
  const int wv = __builtin_amdgcn_readfirstlane(t >> 6);  // wave 0..3

  // h2 row as 16 register pairs (scalar LDS reads, pair in-register)
  v2f h2v[16];
  #pragma unroll
  for (int k = 0; k < 16; ++k) {
    h2v[k].x = h2s[r][2 * k];
    h2v[k].y = h2s[r][2 * k + 1];
  }

  float ldacc = 0.f;

  // ---- layer 3 + spline: 4 d's per thread ----
  #pragma unroll 1
  for (int di = 0; di < 4; ++di) {
    const int dloc = wv * 4 + di;                          // 0..15, uniform
    const int dU = __builtin_amdgcn_readfirstlane(ds * 16 + dloc);
    const float* w3d = W3t + (size_t)dU * (NM * 32);
    const float* b3d = b3t + dU * NM;

    float p[NM];
    #pragma unroll
    for (int m = 0; m < NM; ++m) {
      const v2f* wrow = reinterpret_cast<const v2f*>(w3d + m * 32);
      v2f acc = {0.f, 0.f};
      #pragma unroll
      for (int kk = 0; kk < 16; ++kk)
        acc += h2v[kk] * wrow[kk];     // ffp-contract=fast -> v_pk_fma_f32
      p[m] = (acc.x + acc.y) + b3d[m];
    }

    const float xv = xz[r][dloc];
    const float xc = fminf(fmaxf(xv, -3.f), 3.f);

    // softmax over widths logits p[0..7]
    float mw = p[0];
    #pragma unroll
    for (int k = 1; k < 8; ++k) mw = fmaxf(mw, p[k]);
    float ew[8], sw = 0.f;
    #pragma unroll
    for (int k = 0; k < 8; ++k) { ew[k] = __expf(p[k] - mw); sw += ew[k]; }
    const float invw = 1.f / sw;

    // softmax over heights logits p[8..15]
    float mh = p[8];
    #pragma unroll
    for (int k = 1; k < 8; ++k) mh = fmaxf(mh, p[8 + k]);
    float eh[8], sh = 0.f;
    #pragma unroll
    for (int k = 0; k < 8; ++k) { eh[k] = __expf(p[8 + k] - mh); sh += eh[k]; }
    const float invh = 1.f / sh;

    const float WSC = 1.0f - 1e-3f * 8.0f;   // 1 - MIN_BIN_WIDTH*K
    float cumw[9], cumh[9];
    cumw[0] = -3.f; cumh[0] = -3.f;
    float cw = 0.f, ch = 0.f;
    #pragma unroll
    for (int k = 0; k < 7; ++k) {
      cw += 1e-3f + WSC * (ew[k] * invw);
      ch += 1e-3f + WSC * (eh[k] * invh);
      cumw[k + 1] = fmaf(6.f, cw, -3.f);
      cumh[k + 1] = fmaf(6.f, ch, -3.f);
    }
    cumw[8] = 3.f; cumh[8] = 3.f;

    float derivs[9];
    derivs[0] = 1.f; derivs[8] = 1.f;
    #pragma unroll
    for (int k = 0; k < 7; ++k) derivs[k + 1] = 1e-3f + softplus_f(p[16 + k]);

    // bin select: idx = sum(xc >= cumw[k]+EPS) - 1, clipped to [0,7]
    float xk = cumw[0], xk1 = cumw[1];
    float yk = cumh[0], yk1 = cumh[1];
    float dk = derivs[0], dk1 = derivs[1];
    #pragma unroll
    for (int k = 1; k < 8; ++k) {
      const bool s = xc >= cumw[k] + 1e-6f;
      xk  = s ? cumw[k]       : xk;
      xk1 = s ? cumw[k + 1]   : xk1;
      yk  = s ? cumh[k]       : yk;
      yk1 = s ? cumh[k + 1]   : yk1;
      dk  = s ? derivs[k]     : dk;
      dk1 = s ? derivs[k + 1] : dk1;
    }

    const float wk = xk1 - xk, hk = yk1 - yk;
    const float invwk = 1.f / wk;
    const float delta = hk * invwk;
    const float theta = (xc - xk) * invwk;
    const float omt = 1.f - theta;
    const float tt = theta * omt;
    const float th2 = theta * theta;
    const float num = hk * (delta * th2 + dk * tt);
    const float den = delta + (dk + dk1 - 2.f * delta) * tt;
    const float yv = yk + num / den;
    const float dnum = delta * delta * (dk1 * th2 + 2.f * delta * tt + dk * omt * omt);
    const float ldv = __logf(dnum) - 2.f * __logf(den);

    const bool inside = (xv >= -3.f) && (xv <= 3.f);
    xz[r][dloc] = inside ? yv : xv;          // overlay: z replaces x (same owner)
    ldacc += inside ? ldv : 0.f;
  }

  ldp[wv][r] = ldacc;
  __syncthreads();

  // coalesced z write
  {
    const int row = t >> 2, c4 = (t & 3) * 4;
    const float4 v = make_float4(xz[row][c4 + 0], xz[row][c4 + 1],
                                 xz[row][c4 + 2], xz[row][c4 + 3]);
    *reinterpret_cast<float4*>(
        out + ((size_t)(b0 + row) * 64) + ds * 16 + c4) = v;
  }
  // log-det partial: one atomicAdd per row per d-slice (zeroed by kernel 1)
  if (t < 64) {
    const float s = ldp[0][t] + ldp[1][t] + ldp[2][t] + ldp[3][t];
    atomicAdd(&out[(size_t)B * 64 + b0 + t], s);
  }
}

extern "C" void kernel_launch(void* const* d_in, const int* in_sizes, int n_in,
                              void* d_out, int out_size, void* d_ws, size_t ws_size,
                              hipStream_t stream) {
  const float* x  = (const float*)d_in[0];
  const float* W1 = (const float*)d_in[1];
  const float* b1 = (const float*)d_in[2];
  const float* W2 = (const float*)d_in[3];
  const float* b2 = (const float*)d_in[4];
  const float* W3 = (const float*)d_in[5];
  const float* b3 = (const float*)d_in[6];
  float* out = (float*)d_out;
  float* ws  = (float*)d_ws;

  float* W3t = ws;                       // 47104 floats
  float* b3t = ws + 47104;               // 1472
  float* h2w = ws + 49152;               // B*32 floats (16B-aligned offset)

  const int B = in_sizes[0] / 64;        // 32768

  h2_prep_kernel<<<B / 64, 1024, 0, stream>>>(
      x, W1, b1, W2, b2, W3, b3, h2w, W3t, b3t, out + (size_t)B * 64, B);

  spline_kernel<<<(B / 64) * 4, 256, 0, stream>>>(
      x, h2w, W3t, b3t, out, B);
}

// Round 9
// 153.415 us; speedup vs baseline: 2.9950x; 1.0721x over previous
//
#include <hip/hip_runtime.h>

#define NM 23        // 3*K - 1, K = 8

__device__ __forceinline__ float softplus_f(float v) {
  // stable: max(v,0) + log(1 + exp(-|v|))
  return fmaxf(v, 0.f) + __logf(1.f + __expf(-fabsf(v)));
}

// ---------------------------------------------------------------------------
// Prep (184 blocks): pre-masked weights, no transposes except W3.
//   W1m[i][d]      = W1[i][d]  * ((i%63) >= d)       4096, raw layout
//   W2m[j][i]      = W2[j][i]  * ((i%63) <= j)       2048, raw layout
//   W3t2[d][k][m]  = W3[(m*64+d)*32+k] * (k < d)     47104, m-minor(23)!
//   b3t[d][m]      = b3[m*64+d]                      1472
// W3t2's m-minor layout enables k-outer/m-inner: one h2 LDS read feeds 23
// FMAs (R8 pathology: m-outer forced ~368 LDS rereads per d at VGPR=40).
// Coverage: 184*256 = 47104 exactly (R4 lesson).
// ---------------------------------------------------------------------------
__global__ __launch_bounds__(256) void prep_kernel(
    const float* __restrict__ W1, const float* __restrict__ W2,
    const float* __restrict__ W3, const float* __restrict__ b3,
    float* __restrict__ W1m, float* __restrict__ W2m,
    float* __restrict__ W3t2, float* __restrict__ b3t) {
  const int idx = blockIdx.x * 256 + threadIdx.x;
  if (idx < 64 * 64) {                        // W1m
    const int i = idx >> 6, d = idx & 63;
    W1m[idx] = ((i % 63) >= d) ? W1[idx] : 0.f;
  }
  if (idx < 32 * 64) {                        // W2m
    const int j = idx >> 6, i = idx & 63;
    W2m[idx] = ((i % 63) <= j) ? W2[idx] : 0.f;
  }
  if (idx < 64 * 32 * NM) {                   // W3t2[d][k][m]
    const int d = idx / (32 * NM);
    const int rem = idx - d * (32 * NM);
    const int k = rem / NM, m = rem - k * NM;
    W3t2[idx] = (k < d) ? W3[(m * 64 + d) * 32 + k] : 0.f;
  }
  if (idx < 64 * NM) {                        // b3t[d][m]
    const int d = idx / NM, m = idx - d * NM;
    b3t[idx] = b3[m * 64 + d];
  }
}

// ---------------------------------------------------------------------------
// Fused kernel: 64 rows/block, 1024 threads (16 waves), lane = row.
// Layers 1+2 (pure fmac, pre-masked weights), layer 3 k-outer/m-inner with
// acc[23] in regs, spline, z + per-row log-det all in-block (no atomics).
// Grid 512 x 2 blocks/CU target (launch_bounds (1024,4) ~ 64 VGPR cap).
// ---------------------------------------------------------------------------
__global__ __launch_bounds__(1024, 4) void fused_kernel(
    const float* __restrict__ x,
    const float* __restrict__ W1m, const float* __restrict__ b1,
    const float* __restrict__ W2m, const float* __restrict__ b2,
    const float* __restrict__ W3t2, const float* __restrict__ b3t,
    float* __restrict__ out, int B) {
  __shared__ float xs[64][65];    // x, kept through spline (exact fp32 x)
  __shared__ float h1s[64][65];   // h1; reused as z staging after layer 2
  __shared__ float h2s[64][33];
  __shared__ float ldp[16][64];

  const int t = threadIdx.x;
  const int b0 = blockIdx.x * 64;

  // ---- stage x tile: one float4 per thread (1024 thr = 64x64) ----
  {
    const int rr = t >> 4, c4 = (t & 15) * 4;
    const float4 v =
        *reinterpret_cast<const float4*>(x + (size_t)b0 * 64 + (size_t)t * 4);
    xs[rr][c4 + 0] = v.x; xs[rr][c4 + 1] = v.y;
    xs[rr][c4 + 2] = v.z; xs[rr][c4 + 3] = v.w;
  }
  __syncthreads();

  const int r  = t & 63;                                  // lane = row
  const int wv = __builtin_amdgcn_readfirstlane(t >> 6);  // wave 0..15

  // ---- layer 1: i in [wv*4, wv*4+4), pure fmac on pre-masked W1m ----
  {
    const int iBase = wv * 4;
    float acc1[4];
    #pragma unroll
    for (int ii = 0; ii < 4; ++ii) acc1[ii] = b1[iBase + ii];
    #pragma unroll 8
    for (int dd = 0; dd < 64; ++dd) {
      const float xv = xs[r][dd];
      const float* wrow = W1m + dd + iBase * 64;  // W1m[i][dd], i uniform
      #pragma unroll
      for (int ii = 0; ii < 4; ++ii)
        acc1[ii] = fmaf(xv, wrow[ii * 64], acc1[ii]);
    }
    #pragma unroll
    for (int ii = 0; ii < 4; ++ii) h1s[r][iBase + ii] = fmaxf(acc1[ii], 0.f);
  }
  __syncthreads();

  // ---- layer 2: j in [wv*2, wv*2+2), pure fmac on pre-masked W2m ----
  {
    const int jBase = wv * 2;
    float acc2[2];
    #pragma unroll
    for (int jj = 0; jj < 2; ++jj) acc2[jj] = b2[jBase + jj];
    #pragma unroll 8
    for (int i2 = 0; i2 < 64; ++i2) {
      const float hv = h1s[r][i2];
      const float* wrow = W2m + i2 + jBase * 64;  // W2m[j][i2], j uniform
      #pragma unroll
      for (int jj = 0; jj < 2; ++jj)
        acc2[jj] = fmaf(hv, wrow[jj * 64], acc2[jj]);
    }
    #pragma unroll
    for (int jj = 0; jj < 2; ++jj)
      h2s[r][jBase + jj] = fmaxf(acc2[jj], 0.f);
  }
  __syncthreads();   // h2s ready; h1s dead -> reusable as z staging

  float ldacc = 0.f;

  // ---- layer 3 + spline: 4 d's per thread, k-outer / m-inner ----
  #pragma unroll 1
  for (int di = 0; di < 4; ++di) {
    const int dU = __builtin_amdgcn_readfirstlane(wv * 4 + di);
    const float* w3d = W3t2 + dU * (32 * NM);   // [k][m], m-minor, uniform
    const float* b3d = b3t + dU * NM;

    float acc[NM];
    #pragma unroll
    for (int m = 0; m < NM; ++m) acc[m] = b3d[m];
    #pragma unroll
    for (int kk = 0; kk < 32; ++kk) {
      const float hv = h2s[r][kk];              // ONE LDS read per k
      const float* wrow = w3d + kk * NM;
      #pragma unroll
      for (int m = 0; m < NM; ++m)
        acc[m] = fmaf(hv, wrow[m], acc[m]);     // scalar-weight fmac
    }

    const float xv = xs[r][dU];
    const float xc = fminf(fmaxf(xv, -3.f), 3.f);

    // softmax over widths logits acc[0..7]
    float mw = acc[0];
    #pragma unroll
    for (int k = 1; k < 8; ++k) mw = fmaxf(mw, acc[k]);
    float ew[8], sw = 0.f;
    #pragma unroll
    for (int k = 0; k < 8; ++k) { ew[k] = __expf(acc[k] - mw); sw += ew[k]; }
    const float invw = 1.f / sw;

    // softmax over heights logits acc[8..15]
    float mh = acc[8];
    #pragma unroll
    for (int k = 1; k < 8; ++k) mh = fmaxf(mh, acc[8 + k]);
    float eh[8], sh = 0.f;
    #pragma unroll
    for (int k = 0; k < 8; ++k) { eh[k] = __expf(acc[8 + k] - mh); sh += eh[k]; }
    const float invh = 1.f / sh;

    const float WSC = 1.0f - 1e-3f * 8.0f;   // 1 - MIN_BIN_WIDTH*K
    float cumw[9], cumh[9];
    cumw[0] = -3.f; cumh[0] = -3.f;
    float cw = 0.f, ch = 0.f;
    #pragma unroll
    for (int k = 0; k < 7; ++k) {
      cw += 1e-3f + WSC * (ew[k] * invw);
      ch += 1e-3f + WSC * (eh[k] * invh);
      cumw[k + 1] = fmaf(6.f, cw, -3.f);
      cumh[k + 1] = fmaf(6.f, ch, -3.f);
    }
    cumw[8] = 3.f; cumh[8] = 3.f;

    float derivs[9];
    derivs[0] = 1.f; derivs[8] = 1.f;
    #pragma unroll
    for (int k = 0; k < 7; ++k) derivs[k + 1] = 1e-3f + softplus_f(acc[16 + k]);

    // bin select: idx = sum(xc >= cumw[k]+EPS) - 1, clipped to [0,7]
    float xk = cumw[0], xk1 = cumw[1];
    float yk = cumh[0], yk1 = cumh[1];
    float dk = derivs[0], dk1 = derivs[1];
    #pragma unroll
    for (int k = 1; k < 8; ++k) {
      const bool s = xc >= cumw[k] + 1e-6f;
      xk  = s ? cumw[k]       : xk;
      xk1 = s ? cumw[k + 1]   : xk1;
      yk  = s ? cumh[k]       : yk;
      yk1 = s ? cumh[k + 1]   : yk1;
      dk  = s ? derivs[k]     : dk;
      dk1 = s ? derivs[k + 1] : dk1;
    }

    const float wk = xk1 - xk, hk = yk1 - yk;
    const float invwk = 1.f / wk;
    const float delta = hk * invwk;
    const float theta = (xc - xk) * invwk;
    const float omt = 1.f - theta;
    const float tt = theta * omt;
    const float th2 = theta * theta;
    const float num = hk * (delta * th2 + dk * tt);
    const float den = delta + (dk + dk1 - 2.f * delta) * tt;
    const float yv = yk + num / den;
    const float dnum = delta * delta * (dk1 * th2 + 2.f * delta * tt + dk * omt * omt);
    const float ldv = __logf(dnum) - 2.f * __logf(den);

    const bool inside = (xv >= -3.f) && (xv <= 3.f);
    h1s[r][dU] = inside ? yv : xv;           // z staging in dead h1s
    ldacc += inside ? ldv : 0.f;
  }

  ldp[wv][r] = ldacc;
  __syncthreads();

  // ---- coalesced z write: one float4 per thread ----
  {
    const int rr = t >> 4, c4 = (t & 15) * 4;
    const float4 v = make_float4(h1s[rr][c4 + 0], h1s[rr][c4 + 1],
                                 h1s[rr][c4 + 2], h1s[rr][c4 + 3]);
    *reinterpret_cast<float4*>(out + (size_t)b0 * 64 + (size_t)t * 4) = v;
  }
  // ---- per-row log-det: complete within block, direct store ----
  if (t < 64) {
    float s = 0.f;
    #pragma unroll
    for (int w = 0; w < 16; ++w) s += ldp[w][t];
    out[(size_t)B * 64 + b0 + t] = s;
  }
}

extern "C" void kernel_launch(void* const* d_in, const int* in_sizes, int n_in,
                              void* d_out, int out_size, void* d_ws, size_t ws_size,
                              hipStream_t stream) {
  const float* x  = (const float*)d_in[0];
  const float* W1 = (const float*)d_in[1];
  const float* b1 = (const float*)d_in[2];
  const float* W2 = (const float*)d_in[3];
  const float* b2 = (const float*)d_in[4];
  const float* W3 = (const float*)d_in[5];
  const float* b3 = (const float*)d_in[6];
  float* out = (float*)d_out;
  float* ws  = (float*)d_ws;

  float* W1m  = ws;                      // 4096
  float* W2m  = ws + 4096;               // 2048
  float* W3t2 = ws + 6144;               // 47104
  float* b3t  = ws + 53248;              // 1472

  const int B = in_sizes[0] / 64;        // 32768

  prep_kernel<<<184, 256, 0, stream>>>(W1, W2, W3, b3, W1m, W2m, W3t2, b3t);

  fused_kernel<<<B / 64, 1024, 0, stream>>>(
      x, W1m, b1, W2m, b2, W3t2, b3t, out, B);
}